// Round 2
// baseline (14318.558 us; speedup 1.0000x reference)
//
#include <hip/hip_runtime.h>
#include <hip/hip_bf16.h>
#include <stdint.h>

typedef uint32_t u32;
typedef uint16_t u16;
typedef uint8_t  u8;
typedef float f32x4 __attribute__((ext_vector_type(4)));
typedef short s16x8 __attribute__((ext_vector_type(8)));

#define TSEQ 2048
#define NB   32
#define HD   512
#define CHUNK 128
#define NCHUNK (TSEQ/CHUNK)

// ---- workspace layout (bytes) ----
static constexpr size_t OFF_WREC  = 0;
static constexpr size_t SZ_WREC   = (size_t)2*32*3*16*2*64*16;   // 6,291,456
static constexpr size_t OFF_WPROJ = OFF_WREC + SZ_WREC;
static constexpr size_t SZ_WPROJ  = (size_t)2*96*32*64*16;       // 6,291,456
static constexpr size_t OFF_PROJ  = OFF_WPROJ + SZ_WPROJ;
static constexpr size_t SZ_PROJ   = (size_t)2*3*512*CHUNK*NB*4;  // 50,331,648
static constexpr size_t OFF_COMM  = OFF_PROJ + SZ_PROJ;
static constexpr size_t SZ_COMM   = (size_t)2*CHUNK*NB*256*4;    // 8,388,608
static constexpr size_t OFF_FLAGS = OFF_COMM + SZ_COMM;
static constexpr size_t SZ_FLAGS  = (size_t)2*CHUNK*32*4;        // 32,768
static constexpr size_t OFF_STATE = OFF_FLAGS + SZ_FLAGS;
static constexpr size_t SZ_STATE  = (size_t)2*NB*HD*4;           // 131,072

struct P {
  const float *x;
  const float *Wri_f,*Wci_f,*Wni_f,*Wrh_f,*Wch_f,*Wnh_f,*br_f,*bi_f,*bni_f,*bnh_f;
  const float *Wri_b,*Wci_b,*Wni_b,*Wrh_b,*Wch_b,*Wnh_b,*br_b,*bi_b,*bni_b,*bnh_b;
  float *out;
  u16  *wrec, *wproj;
  float *proj;
  u32  *comm, *flags;
  float *state;
};

__device__ __forceinline__ f32x4 MFMA(s16x8 a, s16x8 b, f32x4 c){
  return __builtin_amdgcn_mfma_f32_16x16x32_bf16(a, b, c, 0, 0, 0);
}
__device__ __forceinline__ s16x8 as_frag(uint4 v){ return __builtin_bit_cast(s16x8, v); }
__device__ __forceinline__ u16 bf16hi(float v){ return __bfloat16_as_ushort(__float2bfloat16(v)); }
__device__ __forceinline__ u32 pk2(float a, float b){
  return (u32)bf16hi(a) | ((u32)bf16hi(b)<<16);
}
__device__ __forceinline__ float sigm(float x){
  return 1.f/(1.f + __builtin_amdgcn_exp2f(-1.4426950408889634f*x));
}
__device__ __forceinline__ float tanh_(float x){
  return 2.f/(1.f + __builtin_amdgcn_exp2f(-2.8853900817779268f*x)) - 1.f;
}

// ================= PREP: weights -> hi/lo bf16 MFMA-fragment order ==========
__global__ __launch_bounds__(256) void k_prep(P p){
  int sub = blockIdx.x*4 + (threadIdx.x>>6);   // lane-block id, 0..12287
  int gl  = threadIdx.x & 63;
  u16 ob[8];
  if (sub < 6144){
    // recurrent weights: flat = (((d*32+fbw)*3+gate)*16+kk)*2+pass
    int lb = sub;
    int pass = lb & 1;
    int t1 = lb >> 1;      int kk = t1 & 15;
    int t2 = t1 >> 4;      int gate = t2 % 3;
    int t3 = t2 / 3;       int fbw = t3 & 31;  int d = t3 >> 5;
    const float* W = gate==0 ? (d? p.Wrh_b : p.Wrh_f)
                   : gate==1 ? (d? p.Wch_b : p.Wch_f)
                             : (d? p.Wnh_b : p.Wnh_f);
    int f = fbw*16 + (gl & 15);
    int kb = kk*32 + ((gl>>4)<<3);
    #pragma unroll
    for (int e=0;e<8;e++){
      float v = W[(size_t)(kb+e)*512 + f];
      float hiF = __bfloat162float(__ushort_as_bfloat16(bf16hi(v)));
      ob[e] = bf16hi(pass ? (v - hiF) : v);
    }
    uint4 o;
    o.x = (u32)ob[0] | ((u32)ob[1]<<16);
    o.y = (u32)ob[2] | ((u32)ob[3]<<16);
    o.z = (u32)ob[4] | ((u32)ob[5]<<16);
    o.w = (u32)ob[6] | ((u32)ob[7]<<16);
    *(uint4*)(p.wrec + (size_t)lb*512 + gl*8) = o;
  } else {
    // input-proj weights: flat = ((d*96+nt)*32+kk), K'=1024 hi/lo-stacked
    int lb = sub - 6144;
    int kk = lb & 31;
    int t  = lb >> 5;   int nt = t % 96;  int d = t / 96;
    int f_in = nt*16 + (gl & 15);
    int gate = f_in >> 9;  int fg = f_in & 511;
    const float* W = gate==0 ? (d? p.Wri_b : p.Wri_f)
                   : gate==1 ? (d? p.Wci_b : p.Wci_f)
                             : (d? p.Wni_b : p.Wni_f);
    int kb = kk*32 + ((gl>>4)<<3);
    #pragma unroll
    for (int e=0;e<8;e++){
      int kp = kb + e;
      int i  = kp & 511;
      int pass = kp >> 9;
      float v = W[(size_t)i*512 + fg];
      float hiF = __bfloat162float(__ushort_as_bfloat16(bf16hi(v)));
      ob[e] = bf16hi(pass ? (v - hiF) : v);
    }
    uint4 o;
    o.x = (u32)ob[0] | ((u32)ob[1]<<16);
    o.y = (u32)ob[2] | ((u32)ob[3]<<16);
    o.z = (u32)ob[4] | ((u32)ob[5]<<16);
    o.w = (u32)ob[6] | ((u32)ob[7]<<16);
    *(uint4*)(p.wproj + (size_t)lb*512 + gl*8) = o;
  }
}

// ================= PROJ GEMM: x @ [Whi;Wlo] + bias, per chunk ===============
// grid: 32 (mtile) x 6 (ntile/dir) x 2 (dir) = 384 blocks of 256
__global__ __launch_bounds__(256,2) void k_proj(P p, int c){
  int bid = blockIdx.x;
  int mtile = bid & 31;
  int rest  = bid >> 5;        // 0..11
  int nt2   = rest % 6;
  int d     = rest / 6;
  int base_t = d ? (TSEQ - (c+1)*CHUNK) : c*CHUNK;
  int tid = threadIdx.x; int w = tid>>6; int gl = tid&63;
  int wr = (w>>1)*64, wc = (w&1)*128;
  __shared__ __align__(16) u16 As[2][128*40];   // pad stride 40 u16 (80B)

  f32x4 acc[4][8];
  #pragma unroll
  for (int i=0;i<4;i++)
    #pragma unroll
    for (int j=0;j<8;j++) acc[i][j] = (f32x4){0.f,0.f,0.f,0.f};

  int row = tid>>1, seg = (tid&1)*16;
  size_t growb = ((size_t)base_t*32 + (size_t)mtile*128 + row)*512;

  // stage kk=0
  {
    int i0 = 0 + seg;
    const float* src = p.x + growb + i0;
    f32x4 v0 = ((const f32x4*)src)[0], v1 = ((const f32x4*)src)[1];
    f32x4 v2 = ((const f32x4*)src)[2], v3 = ((const f32x4*)src)[3];
    u16* dst = &As[0][row*40 + seg];
    uint4 o0, o1;
    o0.x=pk2(v0[0],v0[1]); o0.y=pk2(v0[2],v0[3]); o0.z=pk2(v1[0],v1[1]); o0.w=pk2(v1[2],v1[3]);
    o1.x=pk2(v2[0],v2[1]); o1.y=pk2(v2[2],v2[3]); o1.z=pk2(v3[0],v3[1]); o1.w=pk2(v3[2],v3[3]);
    *(uint4*)dst = o0; *(uint4*)(dst+8) = o1;
  }

  for (int kk=0; kk<32; kk++){
    __syncthreads();
    f32x4 an0={0,0,0,0},an1={0,0,0,0},an2={0,0,0,0},an3={0,0,0,0};
    if (kk+1 < 32){
      int i0 = (((kk+1)*32) & 511) + seg;
      const float* src = p.x + growb + i0;
      an0 = ((const f32x4*)src)[0]; an1 = ((const f32x4*)src)[1];
      an2 = ((const f32x4*)src)[2]; an3 = ((const f32x4*)src)[3];
    }
    s16x8 bb[8];
    #pragma unroll
    for (int ct=0; ct<8; ct++){
      int nt = nt2*16 + (w&1)*8 + ct;
      bb[ct] = as_frag(*(const uint4*)(p.wproj + ((size_t)((d*96+nt)*32+kk))*512 + gl*8));
    }
    #pragma unroll
    for (int rt2=0; rt2<4; rt2++){
      s16x8 af = as_frag(*(const uint4*)((const char*)&As[kk&1][0]
                    + (size_t)(wr + rt2*16 + (gl&15))*80 + ((gl>>4)<<4)));
      #pragma unroll
      for (int ct=0; ct<8; ct++) acc[rt2][ct] = MFMA(af, bb[ct], acc[rt2][ct]);
    }
    if (kk+1 < 32){
      u16* dst = &As[(kk+1)&1][row*40 + seg];
      uint4 o0, o1;
      o0.x=pk2(an0[0],an0[1]); o0.y=pk2(an0[2],an0[3]); o0.z=pk2(an1[0],an1[1]); o0.w=pk2(an1[2],an1[3]);
      o1.x=pk2(an2[0],an2[1]); o1.y=pk2(an2[2],an2[3]); o1.z=pk2(an3[0],an3[1]); o1.w=pk2(an3[2],an3[3]);
      *(uint4*)dst = o0; *(uint4*)(dst+8) = o1;
    }
  }

  // epilogue: + bias, write [d][gate][fg][s][b] fp32 (b-contiguous dwordx4)
  #pragma unroll
  for (int ct=0; ct<8; ct++){
    int f_in = nt2*256 + wc + ct*16 + (gl&15);
    int gate = f_in >> 9, fg = f_in & 511;
    const float* bptr = gate==0 ? (d? p.br_b  : p.br_f)
                      : gate==1 ? (d? p.bi_b  : p.bi_f)
                                : (d? p.bni_b : p.bni_f);
    float bias = bptr[fg];
    #pragma unroll
    for (int rt2=0; rt2<4; rt2++){
      int row_in = wr + rt2*16 + ((gl>>4)<<2);
      int trel = (mtile*128 + row_in) >> 5;
      int sst  = d ? (CHUNK-1-trel) : trel;
      int b0   = row_in & 31;
      f32x4 o = acc[rt2][ct];
      o[0]+=bias; o[1]+=bias; o[2]+=bias; o[3]+=bias;
      *(f32x4*)(p.proj + ((size_t)(((d*3+gate)*512+fg)*CHUNK + sst))*32 + b0) = o;
    }
  }
}

// ================= REC: persistent recurrence over one chunk ================
__device__ __forceinline__ void gather_h(const P& p, int d, int s, int tid, u16* hplane){
  const u32* cb = p.comm + (((size_t)d*CHUNK + s)<<13);
  #pragma unroll
  for (int i=0;i<16;i++){
    u32 u = (u32)tid + 512u*i;
    u32 v = __hip_atomic_load((u32*)(cb + u), __ATOMIC_RELAXED, __HIP_MEMORY_SCOPE_AGENT);
    u32 b2 = u>>8, r2 = u&255;
    u32 ba = (b2<<10) + (r2<<2);
    ba ^= (b2&7u)<<4;                       // XOR swizzle (matches read side)
    *(u32*)((char*)hplane + ba) = v;
  }
}

// grid: 64 blocks (2 dirs x 32 feature-blocks) of 512 threads
__global__ __launch_bounds__(512,1) void k_rec(P p, int c){
  const int bid = blockIdx.x;
  const int d   = bid >> 5;
  const int fbw = bid & 31;
  const int tid = threadIdx.x;
  const int w   = tid >> 6;
  const int gl  = tid & 63;
  __shared__ __align__(16) u16 hplane[32*512];  // swizzled bf16 h, 32KB
  __shared__ float exch[4][32][17];             // r, c, nh, gn
  __shared__ float hstate[32][16];              // own fp32 state

  const int gate = w>>1, rt = w&1;              // valid for w<6
  s16x8 wf[16][2];
  if (w < 6){
    const u16* wb = p.wrec + ((size_t)(((d*32+fbw)*3+gate)*16))*2*512;
    #pragma unroll
    for (int kk=0;kk<16;kk++)
      #pragma unroll
      for (int ps=0;ps<2;ps++)
        wf[kk][ps] = as_frag(*(const uint4*)(wb + (size_t)(kk*2+ps)*512 + gl*8));
  }
  float bnhv = 0.f;
  if (w < 6 && gate == 2) bnhv = (d? p.bnh_b : p.bnh_f)[fbw*16 + (gl&15)];

  if (c == 0){
    #pragma unroll
    for (int i=0;i<16;i++) ((u32*)hplane)[tid + 512*i] = 0u;
    hstate[tid>>4][tid&15] = 0.f;
  } else {
    hstate[tid>>4][tid&15] = p.state[((size_t)(d*32 + (tid>>4)))*512 + fbw*16 + (tid&15)];
    gather_h(p, d, CHUNK-1, tid, hplane);
  }
  __syncthreads();

  for (int s=0; s<CHUNK; s++){
    const int tg = c*CHUNK + s;
    const int tout = d ? (TSEQ-1-tg) : tg;

    if (w < 6){
      const int f = fbw*16 + (gl&15);
      const float* pp = p.proj + ((size_t)(((d*3+gate)*512 + f)*CHUNK + s))*32
                        + rt*16 + ((gl>>4)<<2);
      f32x4 pj = *(const f32x4*)pp;
      f32x4 a0 = (f32x4){0,0,0,0}, a1 = (f32x4){0,0,0,0};
      #pragma unroll
      for (int kk=0;kk<16;kk++){
        u32 ba = ((u32)(rt*16 + (gl&15))<<10) + ((u32)kk<<6) + (((u32)(gl>>4))<<4);
        ba ^= ((u32)(gl&7))<<4;
        s16x8 af = as_frag(*(const uint4*)((const char*)hplane + ba));
        if (kk & 1){ a1 = MFMA(af, wf[kk][0], a1); a1 = MFMA(af, wf[kk][1], a1); }
        else       { a0 = MFMA(af, wf[kk][0], a0); a0 = MFMA(af, wf[kk][1], a0); }
      }
      f32x4 acc = a0 + a1;
      const int brow = rt*16 + ((gl>>4)<<2);
      if (gate == 2){
        #pragma unroll
        for (int r2=0;r2<4;r2++){
          exch[2][brow+r2][gl&15] = acc[r2] + bnhv;
          exch[3][brow+r2][gl&15] = pj[r2];
        }
      } else {
        #pragma unroll
        for (int r2=0;r2<4;r2++) exch[gate][brow+r2][gl&15] = acc[r2] + pj[r2];
      }
    }
    __syncthreads();                                        // (1)

    {
      const int b = tid>>4, fl = tid&15;
      float rg = sigm(exch[0][b][fl]);
      float cg = sigm(exch[1][b][fl]);
      float n  = tanh_(exch[3][b][fl] + rg*exch[2][b][fl]);
      float hp = hstate[b][fl];
      float hn = n + cg*(hp - n);
      hstate[b][fl] = hn;
      p.out[(size_t)tout*32768 + b*1024 + d*512 + fbw*16 + fl] = hn;
      u32 hb = (u32)bf16hi(hn);
      u32 ob = (u32)__shfl_xor((int)hb, 1);
      if ((tid & 1) == 0){
        u32 pk = hb | (ob<<16);
        u32* cp = p.comm + (((size_t)d*CHUNK + s)<<13) + (u32)(b*256 + fbw*8 + (fl>>1));
        __hip_atomic_store(cp, pk, __ATOMIC_RELAXED, __HIP_MEMORY_SCOPE_AGENT);
      }
    }
    __builtin_amdgcn_s_waitcnt(0);   // ensure each thread's comm stores acked
    __syncthreads();                                        // (2)
    if (tid == 0){
      __hip_atomic_store(p.flags + (size_t)(d*CHUNK+s)*32 + fbw, 1u,
                         __ATOMIC_RELAXED, __HIP_MEMORY_SCOPE_AGENT);
    }
    if (w == 0){
      u32* fb_ = p.flags + (size_t)(d*CHUNK+s)*32;
      while (true){
        u32 v = (gl < 32)
          ? __hip_atomic_load(fb_ + gl, __ATOMIC_RELAXED, __HIP_MEMORY_SCOPE_AGENT)
          : 1u;
        if (!__ballot(v == 0u)) break;
        __builtin_amdgcn_s_sleep(1);
      }
    }
    __syncthreads();                                        // (3)
    gather_h(p, d, s, tid, hplane);
    __syncthreads();                                        // (4)
  }
  p.state[((size_t)(d*32 + (tid>>4)))*512 + fbw*16 + (tid&15)] = hstate[tid>>4][tid&15];
}

// =========================== launch =========================================
extern "C" void kernel_launch(void* const* d_in, const int* in_sizes, int n_in,
                              void* d_out, int out_size, void* d_ws, size_t ws_size,
                              hipStream_t stream){
  (void)in_sizes; (void)n_in; (void)out_size; (void)ws_size;
  P p;
  p.x     = (const float*)d_in[0];
  p.Wri_f = (const float*)d_in[1];  p.Wci_f = (const float*)d_in[2];
  p.Wni_f = (const float*)d_in[3];  p.Wrh_f = (const float*)d_in[4];
  p.Wch_f = (const float*)d_in[5];  p.Wnh_f = (const float*)d_in[6];
  p.br_f  = (const float*)d_in[7];  p.bi_f  = (const float*)d_in[8];
  p.bni_f = (const float*)d_in[9];  p.bnh_f = (const float*)d_in[10];
  p.Wri_b = (const float*)d_in[11]; p.Wci_b = (const float*)d_in[12];
  p.Wni_b = (const float*)d_in[13]; p.Wrh_b = (const float*)d_in[14];
  p.Wch_b = (const float*)d_in[15]; p.Wnh_b = (const float*)d_in[16];
  p.br_b  = (const float*)d_in[17]; p.bi_b  = (const float*)d_in[18];
  p.bni_b = (const float*)d_in[19]; p.bnh_b = (const float*)d_in[20];
  p.out   = (float*)d_out;
  u8* ws  = (u8*)d_ws;
  p.wrec  = (u16*)(ws + OFF_WREC);
  p.wproj = (u16*)(ws + OFF_WPROJ);
  p.proj  = (float*)(ws + OFF_PROJ);
  p.comm  = (u32*)(ws + OFF_COMM);
  p.flags = (u32*)(ws + OFF_FLAGS);
  p.state = (float*)(ws + OFF_STATE);

  hipLaunchKernelGGL(k_prep, dim3(3072), dim3(256), 0, stream, p);
  for (int c=0; c<NCHUNK; c++){
    hipLaunchKernelGGL(k_proj, dim3(384), dim3(256), 0, stream, p, c);
    hipMemsetAsync(ws + OFF_FLAGS, 0, SZ_FLAGS, stream);
    hipLaunchKernelGGL(k_rec, dim3(64), dim3(512), 0, stream, p, c);
  }
}

// Round 3
// 9014.315 us; speedup vs baseline: 1.5884x; 1.5884x over previous
//
#include <hip/hip_runtime.h>
#include <hip/hip_bf16.h>
#include <stdint.h>

typedef uint32_t u32;
typedef uint16_t u16;
typedef uint8_t  u8;
typedef unsigned long long u64;
typedef float f32x4 __attribute__((ext_vector_type(4)));
typedef short s16x8 __attribute__((ext_vector_type(8)));

#define TSEQ 2048
#define NB   32
#define HD   512
#define CHUNK 128
#define NCHUNK (TSEQ/CHUNK)

// ---- workspace layout (bytes) ----
static constexpr size_t OFF_WREC  = 0;
static constexpr size_t SZ_WREC   = (size_t)2*32*3*16*2*64*16;   // 6,291,456
static constexpr size_t OFF_WPROJ = OFF_WREC + SZ_WREC;
static constexpr size_t SZ_WPROJ  = (size_t)2*96*32*64*16;       // 6,291,456
static constexpr size_t OFF_PROJ  = OFF_WPROJ + SZ_WPROJ;
static constexpr size_t SZ_PROJ   = (size_t)2*3*512*CHUNK*NB*4;  // 50,331,648
static constexpr size_t OFF_COMM  = OFF_PROJ + SZ_PROJ;
static constexpr size_t SZ_COMM   = (size_t)2*CHUNK*8192*8;      // 16,777,216 (tagged u64)
static constexpr size_t OFF_STATE = OFF_COMM + SZ_COMM;
static constexpr size_t SZ_STATE  = (size_t)2*NB*HD*4;           // 131,072

struct P {
  const float *x;
  const float *Wri_f,*Wci_f,*Wni_f,*Wrh_f,*Wch_f,*Wnh_f,*br_f,*bi_f,*bni_f,*bnh_f;
  const float *Wri_b,*Wci_b,*Wni_b,*Wrh_b,*Wch_b,*Wnh_b,*br_b,*bi_b,*bni_b,*bnh_b;
  float *out;
  u16  *wrec, *wproj;
  float *proj;
  u64  *comm;
  float *state;
};

__device__ __forceinline__ f32x4 MFMA(s16x8 a, s16x8 b, f32x4 c){
  return __builtin_amdgcn_mfma_f32_16x16x32_bf16(a, b, c, 0, 0, 0);
}
__device__ __forceinline__ s16x8 as_frag(uint4 v){ return __builtin_bit_cast(s16x8, v); }
__device__ __forceinline__ u16 bf16hi(float v){ return __bfloat16_as_ushort(__float2bfloat16(v)); }
__device__ __forceinline__ u32 pk2(float a, float b){
  return (u32)bf16hi(a) | ((u32)bf16hi(b)<<16);
}
__device__ __forceinline__ float sigm(float x){
  return 1.f/(1.f + __builtin_amdgcn_exp2f(-1.4426950408889634f*x));
}
__device__ __forceinline__ float tanh_(float x){
  return 2.f/(1.f + __builtin_amdgcn_exp2f(-2.8853900817779268f*x)) - 1.f;
}

// ================= PREP: weights -> hi/lo bf16 MFMA-fragment order ==========
__global__ __launch_bounds__(256) void k_prep(P p){
  int sub = blockIdx.x*4 + (threadIdx.x>>6);   // lane-block id, 0..12287
  int gl  = threadIdx.x & 63;
  u16 ob[8];
  if (sub < 6144){
    // recurrent weights: flat = (((d*32+fbw)*3+gate)*16+kk)*2+pass
    int lb = sub;
    int pass = lb & 1;
    int t1 = lb >> 1;      int kk = t1 & 15;
    int t2 = t1 >> 4;      int gate = t2 % 3;
    int t3 = t2 / 3;       int fbw = t3 & 31;  int d = t3 >> 5;
    const float* W = gate==0 ? (d? p.Wrh_b : p.Wrh_f)
                   : gate==1 ? (d? p.Wch_b : p.Wch_f)
                             : (d? p.Wnh_b : p.Wnh_f);
    int f = fbw*16 + (gl & 15);
    int kb = kk*32 + ((gl>>4)<<3);
    #pragma unroll
    for (int e=0;e<8;e++){
      float v = W[(size_t)(kb+e)*512 + f];
      float hiF = __bfloat162float(__ushort_as_bfloat16(bf16hi(v)));
      ob[e] = bf16hi(pass ? (v - hiF) : v);
    }
    uint4 o;
    o.x = (u32)ob[0] | ((u32)ob[1]<<16);
    o.y = (u32)ob[2] | ((u32)ob[3]<<16);
    o.z = (u32)ob[4] | ((u32)ob[5]<<16);
    o.w = (u32)ob[6] | ((u32)ob[7]<<16);
    *(uint4*)(p.wrec + (size_t)lb*512 + gl*8) = o;
  } else {
    // input-proj weights: flat = ((d*96+nt)*32+kk), K'=1024 hi/lo-stacked
    int lb = sub - 6144;
    int kk = lb & 31;
    int t  = lb >> 5;   int nt = t % 96;  int d = t / 96;
    int f_in = nt*16 + (gl & 15);
    int gate = f_in >> 9;  int fg = f_in & 511;
    const float* W = gate==0 ? (d? p.Wri_b : p.Wri_f)
                   : gate==1 ? (d? p.Wci_b : p.Wci_f)
                             : (d? p.Wni_b : p.Wni_f);
    int kb = kk*32 + ((gl>>4)<<3);
    #pragma unroll
    for (int e=0;e<8;e++){
      int kp = kb + e;
      int i  = kp & 511;
      int pass = kp >> 9;
      float v = W[(size_t)i*512 + fg];
      float hiF = __bfloat162float(__ushort_as_bfloat16(bf16hi(v)));
      ob[e] = bf16hi(pass ? (v - hiF) : v);
    }
    uint4 o;
    o.x = (u32)ob[0] | ((u32)ob[1]<<16);
    o.y = (u32)ob[2] | ((u32)ob[3]<<16);
    o.z = (u32)ob[4] | ((u32)ob[5]<<16);
    o.w = (u32)ob[6] | ((u32)ob[7]<<16);
    *(uint4*)(p.wproj + (size_t)lb*512 + gl*8) = o;
  }
}

// ================= PROJ GEMM: x @ [Whi;Wlo] + bias, per chunk ===============
// grid: 32 (mtile) x 6 (ntile/dir) x 2 (dir) = 384 blocks of 256
__global__ __launch_bounds__(256,2) void k_proj(P p, int c){
  int bid = blockIdx.x;
  int mtile = bid & 31;
  int rest  = bid >> 5;        // 0..11
  int nt2   = rest % 6;
  int d     = rest / 6;
  int base_t = d ? (TSEQ - (c+1)*CHUNK) : c*CHUNK;
  int tid = threadIdx.x; int w = tid>>6; int gl = tid&63;
  int wr = (w>>1)*64, wc = (w&1)*128;
  __shared__ __align__(16) u16 As[2][128*40];   // pad stride 40 u16 (80B)

  f32x4 acc[4][8];
  #pragma unroll
  for (int i=0;i<4;i++)
    #pragma unroll
    for (int j=0;j<8;j++) acc[i][j] = (f32x4){0.f,0.f,0.f,0.f};

  int row = tid>>1, seg = (tid&1)*16;
  size_t growb = ((size_t)base_t*32 + (size_t)mtile*128 + row)*512;

  // stage kk=0
  {
    int i0 = 0 + seg;
    const float* src = p.x + growb + i0;
    f32x4 v0 = ((const f32x4*)src)[0], v1 = ((const f32x4*)src)[1];
    f32x4 v2 = ((const f32x4*)src)[2], v3 = ((const f32x4*)src)[3];
    u16* dst = &As[0][row*40 + seg];
    uint4 o0, o1;
    o0.x=pk2(v0[0],v0[1]); o0.y=pk2(v0[2],v0[3]); o0.z=pk2(v1[0],v1[1]); o0.w=pk2(v1[2],v1[3]);
    o1.x=pk2(v2[0],v2[1]); o1.y=pk2(v2[2],v2[3]); o1.z=pk2(v3[0],v3[1]); o1.w=pk2(v3[2],v3[3]);
    *(uint4*)dst = o0; *(uint4*)(dst+8) = o1;
  }

  for (int kk=0; kk<32; kk++){
    __syncthreads();
    f32x4 an0={0,0,0,0},an1={0,0,0,0},an2={0,0,0,0},an3={0,0,0,0};
    if (kk+1 < 32){
      int i0 = (((kk+1)*32) & 511) + seg;
      const float* src = p.x + growb + i0;
      an0 = ((const f32x4*)src)[0]; an1 = ((const f32x4*)src)[1];
      an2 = ((const f32x4*)src)[2]; an3 = ((const f32x4*)src)[3];
    }
    s16x8 bb[8];
    #pragma unroll
    for (int ct=0; ct<8; ct++){
      int nt = nt2*16 + (w&1)*8 + ct;
      bb[ct] = as_frag(*(const uint4*)(p.wproj + ((size_t)((d*96+nt)*32+kk))*512 + gl*8));
    }
    #pragma unroll
    for (int rt2=0; rt2<4; rt2++){
      s16x8 af = as_frag(*(const uint4*)((const char*)&As[kk&1][0]
                    + (size_t)(wr + rt2*16 + (gl&15))*80 + ((gl>>4)<<4)));
      #pragma unroll
      for (int ct=0; ct<8; ct++) acc[rt2][ct] = MFMA(af, bb[ct], acc[rt2][ct]);
    }
    if (kk+1 < 32){
      u16* dst = &As[(kk+1)&1][row*40 + seg];
      uint4 o0, o1;
      o0.x=pk2(an0[0],an0[1]); o0.y=pk2(an0[2],an0[3]); o0.z=pk2(an1[0],an1[1]); o0.w=pk2(an1[2],an1[3]);
      o1.x=pk2(an2[0],an2[1]); o1.y=pk2(an2[2],an2[3]); o1.z=pk2(an3[0],an3[1]); o1.w=pk2(an3[2],an3[3]);
      *(uint4*)dst = o0; *(uint4*)(dst+8) = o1;
    }
  }

  // epilogue: + bias, write [d][gate][fg][s][b] fp32 (b-contiguous dwordx4)
  #pragma unroll
  for (int ct=0; ct<8; ct++){
    int f_in = nt2*256 + wc + ct*16 + (gl&15);
    int gate = f_in >> 9, fg = f_in & 511;
    const float* bptr = gate==0 ? (d? p.br_b  : p.br_f)
                      : gate==1 ? (d? p.bi_b  : p.bi_f)
                                : (d? p.bni_b : p.bni_f);
    float bias = bptr[fg];
    #pragma unroll
    for (int rt2=0; rt2<4; rt2++){
      int row_in = wr + rt2*16 + ((gl>>4)<<2);
      int trel = (mtile*128 + row_in) >> 5;
      int sst  = d ? (CHUNK-1-trel) : trel;
      int b0   = row_in & 31;
      f32x4 o = acc[rt2][ct];
      o[0]+=bias; o[1]+=bias; o[2]+=bias; o[3]+=bias;
      *(f32x4*)(p.proj + ((size_t)(((d*3+gate)*512+fg)*CHUNK + sst))*32 + b0) = o;
    }
  }
}

// ================= REC: persistent recurrence over one chunk ================
// Tagged-comm gather: poll u64 {tag(hi32) | 2xbf16(lo32)} until tag matches,
// scatter payload into swizzled LDS h-plane. One LLC round trip, no fences.
__device__ __forceinline__ void gather_wait(const u64* cb, u32 tag, int tid, u16* hplane){
  u64 v[16];
  u32 pend = 0xFFFFu;
  while (true){
    #pragma unroll
    for (int i=0;i<16;i++){
      if (pend & (1u<<i))
        v[i] = __hip_atomic_load(cb + (u32)tid + (u32)(i<<9),
                                 __ATOMIC_RELAXED, __HIP_MEMORY_SCOPE_AGENT);
    }
    #pragma unroll
    for (int i=0;i<16;i++){
      if ((pend & (1u<<i)) && (u32)(v[i]>>32) == tag){
        u32 u = (u32)tid + (u32)(i<<9);
        u32 b2 = u>>8, r2 = u&255;
        u32 ba = ((b2<<10) + (r2<<2)) ^ ((b2&15u)<<4);   // 16-row XOR swizzle
        *(u32*)((char*)hplane + ba) = (u32)v[i];
        pend &= ~(1u<<i);
      }
    }
    if (!pend) break;
    __builtin_amdgcn_s_sleep(1);
  }
}

// grid: 64 blocks (2 dirs x 32 feature-blocks) of 512 threads
__global__ __launch_bounds__(512,1) void k_rec(P p, int c){
  const int bid = blockIdx.x;
  const int d   = bid >> 5;
  const int fbw = bid & 31;
  const int tid = threadIdx.x;
  const int w   = tid >> 6;
  const int gl  = tid & 63;
  __shared__ __align__(16) u16 hplane[32*512];  // swizzled bf16 h, 32KB
  __shared__ float exch[4][32][17];             // r, c, nh, gn
  __shared__ float hstate[32][16];              // own fp32 state

  const int gate = w>>1, rt = w&1;              // valid for w<6
  s16x8 wf[16][2];
  if (w < 6){
    const u16* wb = p.wrec + ((size_t)(((d*32+fbw)*3+gate)*16))*2*512;
    #pragma unroll
    for (int kk=0;kk<16;kk++)
      #pragma unroll
      for (int ps=0;ps<2;ps++)
        wf[kk][ps] = as_frag(*(const uint4*)(wb + (size_t)(kk*2+ps)*512 + gl*8));
  }
  float bnhv = 0.f;
  if (w < 6 && gate == 2) bnhv = (d? p.bnh_b : p.bnh_f)[fbw*16 + (gl&15)];

  if (c == 0){
    #pragma unroll
    for (int i=0;i<16;i++) ((u32*)hplane)[tid + 512*i] = 0u;
    hstate[tid>>4][tid&15] = 0.f;
  } else {
    hstate[tid>>4][tid&15] = p.state[((size_t)(d*32 + (tid>>4)))*512 + fbw*16 + (tid&15)];
    gather_wait(p.comm + (((size_t)d*CHUNK + (CHUNK-1))<<13), (u32)(c*CHUNK-1), tid, hplane);
  }
  __syncthreads();

  // prefetch proj for s=0
  f32x4 pj = {0,0,0,0};
  if (w < 6){
    const int f = fbw*16 + (gl&15);
    pj = *(const f32x4*)(p.proj + ((size_t)(((d*3+gate)*512 + f)*CHUNK + 0))*32
                         + rt*16 + ((gl>>4)<<2));
  }

  for (int s=0; s<CHUNK; s++){
    const int tg = c*CHUNK + s;
    const int tout = d ? (TSEQ-1-tg) : tg;

    if (w < 6){
      f32x4 a0 = (f32x4){0,0,0,0}, a1 = (f32x4){0,0,0,0};
      #pragma unroll
      for (int kk=0;kk<16;kk++){
        u32 row = (u32)(rt*16 + (gl&15));
        u32 ba = (row<<10) + ((u32)kk<<6) + (((u32)(gl>>4))<<4);
        ba ^= ((u32)(gl&15))<<4;
        s16x8 af = as_frag(*(const uint4*)((const char*)hplane + ba));
        if (kk & 1){ a1 = MFMA(af, wf[kk][0], a1); a1 = MFMA(af, wf[kk][1], a1); }
        else       { a0 = MFMA(af, wf[kk][0], a0); a0 = MFMA(af, wf[kk][1], a0); }
      }
      f32x4 acc = a0 + a1;
      const int brow = rt*16 + ((gl>>4)<<2);
      if (gate == 2){
        #pragma unroll
        for (int r2=0;r2<4;r2++){
          exch[2][brow+r2][gl&15] = acc[r2] + bnhv;
          exch[3][brow+r2][gl&15] = pj[r2];
        }
      } else {
        #pragma unroll
        for (int r2=0;r2<4;r2++) exch[gate][brow+r2][gl&15] = acc[r2] + pj[r2];
      }
    }
    __syncthreads();                                        // B1

    // prefetch proj for s+1 (consumed next iteration; hides under gather)
    f32x4 pjn = {0,0,0,0};
    if (w < 6 && s+1 < CHUNK){
      const int f = fbw*16 + (gl&15);
      pjn = *(const f32x4*)(p.proj + ((size_t)(((d*3+gate)*512 + f)*CHUNK + (s+1)))*32
                            + rt*16 + ((gl>>4)<<2));
    }

    {
      const int b = tid>>4, fl = tid&15;
      float rg = sigm(exch[0][b][fl]);
      float cg = sigm(exch[1][b][fl]);
      float n  = tanh_(exch[3][b][fl] + rg*exch[2][b][fl]);
      float hp = hstate[b][fl];
      float hn = n + cg*(hp - n);
      hstate[b][fl] = hn;
      p.out[(size_t)tout*32768 + b*1024 + d*512 + fbw*16 + fl] = hn;
      u32 hb = (u32)bf16hi(hn);
      u32 ob = (u32)__shfl_xor((int)hb, 1);
      if ((tid & 1) == 0){
        u32 pk = hb | (ob<<16);
        u64 tv = (u64)pk | ((u64)(u32)tg << 32);
        u64* cp = p.comm + (((size_t)d*CHUNK + s)<<13) + (u32)(b*256 + fbw*8 + (fl>>1));
        __hip_atomic_store(cp, tv, __ATOMIC_RELAXED, __HIP_MEMORY_SCOPE_AGENT);
      }
    }
    // gather step-s h from all 32 blocks of this dir (polls tags; 1 round trip)
    gather_wait(p.comm + (((size_t)d*CHUNK + s)<<13), (u32)tg, tid, hplane);
    __syncthreads();                                        // B2
    pj = pjn;
  }
  p.state[((size_t)(d*32 + (tid>>4)))*512 + fbw*16 + (tid&15)] = hstate[tid>>4][tid&15];
}

// =========================== launch =========================================
extern "C" void kernel_launch(void* const* d_in, const int* in_sizes, int n_in,
                              void* d_out, int out_size, void* d_ws, size_t ws_size,
                              hipStream_t stream){
  (void)in_sizes; (void)n_in; (void)out_size; (void)ws_size;
  P p;
  p.x     = (const float*)d_in[0];
  p.Wri_f = (const float*)d_in[1];  p.Wci_f = (const float*)d_in[2];
  p.Wni_f = (const float*)d_in[3];  p.Wrh_f = (const float*)d_in[4];
  p.Wch_f = (const float*)d_in[5];  p.Wnh_f = (const float*)d_in[6];
  p.br_f  = (const float*)d_in[7];  p.bi_f  = (const float*)d_in[8];
  p.bni_f = (const float*)d_in[9];  p.bnh_f = (const float*)d_in[10];
  p.Wri_b = (const float*)d_in[11]; p.Wci_b = (const float*)d_in[12];
  p.Wni_b = (const float*)d_in[13]; p.Wrh_b = (const float*)d_in[14];
  p.Wch_b = (const float*)d_in[15]; p.Wnh_b = (const float*)d_in[16];
  p.br_b  = (const float*)d_in[17]; p.bi_b  = (const float*)d_in[18];
  p.bni_b = (const float*)d_in[19]; p.bnh_b = (const float*)d_in[20];
  p.out   = (float*)d_out;
  u8* ws  = (u8*)d_ws;
  p.wrec  = (u16*)(ws + OFF_WREC);
  p.wproj = (u16*)(ws + OFF_WPROJ);
  p.proj  = (float*)(ws + OFF_PROJ);
  p.comm  = (u64*)(ws + OFF_COMM);
  p.state = (float*)(ws + OFF_STATE);

  hipLaunchKernelGGL(k_prep, dim3(3072), dim3(256), 0, stream, p);
  for (int c=0; c<NCHUNK; c++){
    hipLaunchKernelGGL(k_proj, dim3(384), dim3(256), 0, stream, p, c);
    hipLaunchKernelGGL(k_rec, dim3(64), dim3(512), 0, stream, p, c);
  }
}